// Round 1
// 1466.321 us; speedup vs baseline: 1.3616x; 1.3616x over previous
//
#include <hip/hip_runtime.h>

typedef _Float16 half_t;

#define N_SRCN 50000
#define N_DSTN 50000
#define NE     1600000
#define IN_DIM 128
#define OUT_DIMN 128
#define EDGE_DIMN 64
#define NHEAD  4
#define HDIM   32

// ---------------------------------------------------------------------------
// Workspace layout — 15,005,136 bytes total (< 15,206,144 proven safe).
// Atomic-aggregation replaced by CSR + gather; heads processed in 2 passes so
// hs_half (6.4MB) + perm (6.4MB) fit the <16MiB workspace.
//   hsH    f16[50000*64] @ 0           (6,400,000)  half of h_src @ W_src
//   perm   i32[1.6M]     @ 6,400,000   (6,400,000)  edge ids sorted by dst
//   esrc   f32[200,000]  @ 12,800,000  (  800,000)  per-src logits [N,4]
//   edstl  f32[200,000]  @ 13,600,000  (  800,000)  per-dst logits [N,4]
//   offs   i32[50001]    @ 14,400,000  (  200,016)  CSR row offsets
//   cursor i32[50000]    @ 14,600,016  (  200,000)  scatter cursors
//   counts i32[50000]    @ 14,800,016  (  200,000)  degree histogram
//   c_src  f32[512]      @ 15,000,016  (    2,048)
//   c_dst  f32[512]      @ 15,002,064  (    2,048)
//   c_edgeH f32[256]     @ 15,004,112  (    1,024)  head-major [h*64+k]
// ---------------------------------------------------------------------------

// K1: fold attention vectors through weights.
// c[k*4+h] = sum_d W[k][h*32+d] * a[h][d]; c_edge stored head-major.
__global__ __launch_bounds__(512) void k_combine(
    const float* __restrict__ Wsrc, const float* __restrict__ Wdst,
    const float* __restrict__ Wedge,
    const float* __restrict__ asrc, const float* __restrict__ adst,
    const float* __restrict__ aedge,
    float* __restrict__ c_src, float* __restrict__ c_dst,
    float* __restrict__ c_edgeH) {
    int t = threadIdx.x;           // k = t>>2 (0..127), h = t&3
    int k = t >> 2, h = t & 3;
    float s1 = 0.f, s2 = 0.f;
    #pragma unroll
    for (int d = 0; d < HDIM; ++d) {
        s1 += Wsrc[k * OUT_DIMN + h * HDIM + d] * asrc[h * HDIM + d];
        s2 += Wdst[k * OUT_DIMN + h * HDIM + d] * adst[h * HDIM + d];
    }
    c_src[t] = s1;
    c_dst[t] = s2;
    if (t < EDGE_DIMN * NHEAD) {   // k = 0..63
        float s3 = 0.f;
        #pragma unroll
        for (int d = 0; d < HDIM; ++d)
            s3 += Wedge[k * OUT_DIMN + h * HDIM + d] * aedge[h * HDIM + d];
        c_edgeH[h * EDGE_DIMN + k] = s3;  // [h*64+k]
    }
}

// K2: node logits  out[row][h] = sum_k X[row][k] * c[k*4+h]. One wave per row.
__global__ __launch_bounds__(256) void k_node_logits(
    const float* __restrict__ X, const float* __restrict__ c,
    float* __restrict__ outl, int N) {
    int row = blockIdx.x * 4 + (threadIdx.x >> 6);
    int l = threadIdx.x & 63;
    if (row >= N) return;
    float x0 = X[(size_t)row * IN_DIM + l];
    float x1 = X[(size_t)row * IN_DIM + 64 + l];
    #pragma unroll
    for (int h = 0; h < NHEAD; ++h) {
        float s = x0 * c[l * 4 + h] + x1 * c[(64 + l) * 4 + h];
        #pragma unroll
        for (int off = 32; off; off >>= 1) s += __shfl_xor(s, off, 64);
        if (l == h) outl[(size_t)row * 4 + h] = s;
    }
}

// K3a: degree histogram over dst indices.
__global__ __launch_bounds__(256) void k_hist(
    const int* __restrict__ dstI, int* __restrict__ counts) {
    int e = blockIdx.x * 256 + threadIdx.x;
    if (e < NE) atomicAdd(&counts[dstI[e]], 1);
}

// K3b: exclusive scan of counts -> offs[0..N], cursor copy. Single block.
__global__ __launch_bounds__(1024) void k_scan(
    const int* __restrict__ cnt, int* __restrict__ offs, int* __restrict__ cur) {
    __shared__ int wbase[17];
    __shared__ int carry_s;
    int t = threadIdx.x;
    int lane = t & 63, w = t >> 6;   // 16 waves
    if (t == 0) carry_s = 0;
    __syncthreads();
    for (int base = 0; base < N_DSTN; base += 4096) {
        int idx = base + t * 4;
        int4 c = make_int4(0, 0, 0, 0);
        if (idx < N_DSTN) c = *(const int4*)(cnt + idx);   // N_DSTN%4==0 so no straddle
        int s4 = c.x + c.y + c.z + c.w;
        int incl = s4;
        #pragma unroll
        for (int off = 1; off < 64; off <<= 1) {
            int v = __shfl_up(incl, off, 64);
            if (lane >= off) incl += v;
        }
        if (lane == 63) wbase[w] = incl;
        __syncthreads();
        if (t == 0) {
            int run = 0;
            #pragma unroll
            for (int q = 0; q < 16; ++q) { int v = wbase[q]; wbase[q] = run; run += v; }
            wbase[16] = run;  // chunk total
        }
        __syncthreads();
        int ebase = carry_s + wbase[w] + (incl - s4);
        if (idx < N_DSTN) {
            int4 o;
            int run = ebase;
            o.x = run; run += c.x;
            o.y = run; run += c.y;
            o.z = run; run += c.z;
            o.w = run; run += c.w;
            *(int4*)(offs + idx) = o;
            *(int4*)(cur + idx) = o;
        }
        __syncthreads();
        if (t == 0) carry_s += wbase[16];
        __syncthreads();
    }
    if (t == 0) offs[N_DSTN] = carry_s;
}

// K3c: scatter edge ids into dst-sorted order.
__global__ __launch_bounds__(256) void k_scatter(
    const int* __restrict__ dstI, int* __restrict__ cursor,
    int* __restrict__ perm) {
    int e = blockIdx.x * 256 + threadIdx.x;
    if (e < NE) {
        int d = dstI[e];
        int pos = atomicAdd(&cursor[d], 1);
        perm[pos] = e;
    }
}

// K4: hs_half = (h_src @ W_src)[:, c0:c0+64], stored fp16.
// Tile M=64, N=64, K chunked 64. 256 threads, 4x4 acc per thread.
__global__ __launch_bounds__(256) void k_gemm_half(
    const float* __restrict__ A, const float* __restrict__ W,
    half_t* __restrict__ C, int M, int c0) {
    __shared__ float As[64][68];
    __shared__ float Ws[64][68];
    int t = threadIdx.x;
    int tx = t & 15, ty = t >> 4;
    int rowbase = blockIdx.x * 64;
    float acc[4][4];
    #pragma unroll
    for (int i = 0; i < 4; ++i)
        #pragma unroll
        for (int j = 0; j < 4; ++j) acc[i][j] = 0.f;

    for (int kc = 0; kc < IN_DIM; kc += 64) {
        #pragma unroll
        for (int p = 0; p < 4; ++p) {          // A tile: 64x64
            int flat = p * 1024 + t * 4;
            int r = flat >> 6, ck = flat & 63;
            float4 v = make_float4(0.f, 0.f, 0.f, 0.f);
            if (rowbase + r < M)
                v = *(const float4*)(A + (size_t)(rowbase + r) * IN_DIM + kc + ck);
            *(float4*)(&As[r][ck]) = v;
        }
        #pragma unroll
        for (int p = 0; p < 4; ++p) {          // W tile: 64x64 (cols c0..c0+63)
            int flat = p * 1024 + t * 4;
            int kk = flat >> 6, col = flat & 63;
            *(float4*)(&Ws[kk][col]) =
                *(const float4*)(W + (size_t)(kc + kk) * OUT_DIMN + c0 + col);
        }
        __syncthreads();
        #pragma unroll
        for (int k = 0; k < 64; ++k) {
            float a[4], b[4];
            #pragma unroll
            for (int i = 0; i < 4; ++i) a[i] = As[ty * 4 + i][k];
            #pragma unroll
            for (int j = 0; j < 4; ++j) b[j] = Ws[k][tx + j * 16];
            #pragma unroll
            for (int i = 0; i < 4; ++i)
                #pragma unroll
                for (int j = 0; j < 4; ++j) acc[i][j] += a[i] * b[j];
        }
        __syncthreads();
    }
    #pragma unroll
    for (int i = 0; i < 4; ++i) {
        int row = rowbase + ty * 4 + i;
        if (row < M) {
            #pragma unroll
            for (int j = 0; j < 4; ++j)
                C[(size_t)row * 64 + tx + j * 16] = (half_t)acc[i][j];
        }
    }
}

// K5: gather-aggregate. One wave per dst node; heads (2*pass, 2*pass+1).
// Lane l: group g=l>>5 handles head h=2*pass+g (float2 EF dot + 5 shuffles);
// lane owns output col pass*64+l. Online softmax denominator in registers —
// no atomics, out written exactly once. No max-subtract (logits bounded).
__global__ __launch_bounds__(256) void k_gather(
    const int* __restrict__ offs, const int* __restrict__ perm,
    const int* __restrict__ srcI,
    const float* __restrict__ EF, const float* __restrict__ ceH,
    const float* __restrict__ esrc, const float* __restrict__ edstl,
    const half_t* __restrict__ hsH, float* __restrict__ out, int pass) {
    int d = blockIdx.x * 4 + (threadIdx.x >> 6);
    if (d >= N_DSTN) return;
    int l = threadIdx.x & 63;
    int g = l >> 5;                 // local head 0/1
    int j = l & 31;                 // float2 index into 64-float EF row
    int h = pass * 2 + g;           // global head
    float2 c2 = ((const float2*)(ceH + h * EDGE_DIMN))[j];
    float ed = edstl[(size_t)d * 4 + h];
    int start = offs[d], end = offs[d + 1];
    float acc = 0.f, den = 0.f;
    int eid = (start < end) ? perm[start] : 0;
    int si  = (start < end) ? srcI[eid] : 0;
    for (int i = start; i < end; ++i) {
        int eid_n = 0, si_n = 0;
        if (i + 1 < end) { eid_n = perm[i + 1]; si_n = srcI[eid_n]; }
        float2 v = ((const float2*)(EF + (size_t)eid * EDGE_DIMN))[j];
        float s = v.x * c2.x + v.y * c2.y;
        s += __shfl_xor(s, 1, 64);
        s += __shfl_xor(s, 2, 64);
        s += __shfl_xor(s, 4, 64);
        s += __shfl_xor(s, 8, 64);
        s += __shfl_xor(s, 16, 64);   // 32-lane group reduce: all hold head-h dot
        float z = esrc[(size_t)si * 4 + h] + ed + s;
        z = z > 0.f ? z : 0.2f * z;
        float ez = __expf(z);
        den += ez;
        acc += ez * (float)hsH[(size_t)si * 64 + l];
        eid = eid_n; si = si_n;
    }
    out[(size_t)d * OUT_DIMN + pass * 64 + l] = acc / (den + 1e-8f);
}

extern "C" void kernel_launch(void* const* d_in, const int* in_sizes, int n_in,
                              void* d_out, int out_size, void* d_ws, size_t ws_size,
                              hipStream_t stream) {
    const float* h_src     = (const float*)d_in[0];
    const float* h_dst     = (const float*)d_in[1];
    const float* edge_feat = (const float*)d_in[2];
    const int*   eidx      = (const int*)d_in[3];   // [2, E] int32
    const float* Wsrc      = (const float*)d_in[4];
    const float* Wdst      = (const float*)d_in[5];
    const float* Wedge     = (const float*)d_in[6];
    const float* asrc      = (const float*)d_in[7];
    const float* adst      = (const float*)d_in[8];
    const float* aedge     = (const float*)d_in[9];
    float* out = (float*)d_out;

    char* W = (char*)d_ws;
    half_t* hsH    = (half_t*)(W + 0);
    int*   perm    = (int*)(W + 6400000);
    float* esrc    = (float*)(W + 12800000);
    float* edstl   = (float*)(W + 13600000);
    int*   offs    = (int*)(W + 14400000);
    int*   cursor  = (int*)(W + 14600016);
    int*   counts  = (int*)(W + 14800016);
    float* c_src   = (float*)(W + 15000016);
    float* c_dst   = (float*)(W + 15002064);
    float* c_edgeH = (float*)(W + 15004112);

    const int* srcI = eidx;
    const int* dstI = eidx + NE;

    hipMemsetAsync(counts, 0, N_DSTN * sizeof(int), stream);

    k_combine<<<1, 512, 0, stream>>>(Wsrc, Wdst, Wedge, asrc, adst, aedge,
                                     c_src, c_dst, c_edgeH);
    k_node_logits<<<(N_SRCN + 3) / 4, 256, 0, stream>>>(h_src, c_src, esrc, N_SRCN);
    k_node_logits<<<(N_DSTN + 3) / 4, 256, 0, stream>>>(h_dst, c_dst, edstl, N_DSTN);

    k_hist<<<(NE + 255) / 256, 256, 0, stream>>>(dstI, counts);
    k_scan<<<1, 1024, 0, stream>>>(counts, offs, cursor);
    k_scatter<<<(NE + 255) / 256, 256, 0, stream>>>(dstI, cursor, perm);

    k_gemm_half<<<(N_SRCN + 63) / 64, 256, 0, stream>>>(h_src, Wsrc, hsH, N_SRCN, 0);
    k_gather<<<(N_DSTN + 3) / 4, 256, 0, stream>>>(offs, perm, srcI, edge_feat,
                                                   c_edgeH, esrc, edstl, hsH, out, 0);
    k_gemm_half<<<(N_SRCN + 63) / 64, 256, 0, stream>>>(h_src, Wsrc, hsH, N_SRCN, 64);
    k_gather<<<(N_DSTN + 3) / 4, 256, 0, stream>>>(offs, perm, srcI, edge_feat,
                                                   c_edgeH, esrc, edstl, hsH, out, 1);
}

// Round 2
// 1404.728 us; speedup vs baseline: 1.4213x; 1.0438x over previous
//
#include <hip/hip_runtime.h>

typedef _Float16 half_t;

#define N_SRCN 50000
#define N_DSTN 50000
#define NE     1600000
#define IN_DIM 128
#define OUT_DIMN 128
#define EDGE_DIMN 64
#define NHEAD  4
#define HDIM   32

// 16-lane (DPP row) rotate-add full reduction: after 4 steps every lane in each
// 16-lane row holds the row's sum. Pure VALU — no LDS/DS ops.
#define ROR_ADD(x, CTRL) ((x) + __int_as_float(__builtin_amdgcn_update_dpp( \
    0, __float_as_int(x), (CTRL), 0xF, 0xF, false)))
__device__ __forceinline__ float sum16(float s) {
    s = ROR_ADD(s, 0x121);  // row_ror:1
    s = ROR_ADD(s, 0x122);  // row_ror:2
    s = ROR_ADD(s, 0x124);  // row_ror:4
    s = ROR_ADD(s, 0x128);  // row_ror:8
    return s;
}

// ---------------------------------------------------------------------------
// Workspace layout — 15,005,392 bytes total (< 15,206,144 proven safe).
//   hsH    f16[50000*64] @ 0           (6,400,000)  half of h_src @ W_src
//   perm   i32[1.6M]     @ 6,400,000   (6,400,000)  edge ids sorted by dst
//   esrc   f32[200,000]  @ 12,800,000  (  800,000)  per-src logits [N,4]
//   edstl  f32[200,000]  @ 13,600,000  (  800,000)  per-dst logits [N,4]
//   offs   i32[50001]    @ 14,400,000  (  200,016)  CSR row offsets
//   cursor i32[50000]    @ 14,600,016  (  200,000)  scatter cursors
//   counts i32[50000]    @ 14,800,016  (  200,000)  degree histogram
//   c_srcH f32[512]      @ 15,000,016  (    2,048)  head-major [h*128+k]
//   c_dstH f32[512]      @ 15,002,064  (    2,048)  head-major [h*128+k]
//   c_edgeH f32[256]     @ 15,004,112  (    1,024)  head-major [h*64+k]
//   bsum   i32[64]       @ 15,005,136  (      256)  scan block sums
// ---------------------------------------------------------------------------

// K1: fold attention vectors through weights (head-major outputs).
__global__ __launch_bounds__(512) void k_combine(
    const float* __restrict__ Wsrc, const float* __restrict__ Wdst,
    const float* __restrict__ Wedge,
    const float* __restrict__ asrc, const float* __restrict__ adst,
    const float* __restrict__ aedge,
    float* __restrict__ c_srcH, float* __restrict__ c_dstH,
    float* __restrict__ c_edgeH) {
    int t = threadIdx.x;           // k = t>>2 (0..127), h = t&3
    int k = t >> 2, h = t & 3;
    float s1 = 0.f, s2 = 0.f;
    #pragma unroll
    for (int d = 0; d < HDIM; ++d) {
        s1 += Wsrc[k * OUT_DIMN + h * HDIM + d] * asrc[h * HDIM + d];
        s2 += Wdst[k * OUT_DIMN + h * HDIM + d] * adst[h * HDIM + d];
    }
    c_srcH[h * IN_DIM + k] = s1;
    c_dstH[h * IN_DIM + k] = s2;
    if (t < EDGE_DIMN * NHEAD) {   // k = 0..63
        float s3 = 0.f;
        #pragma unroll
        for (int d = 0; d < HDIM; ++d)
            s3 += Wedge[k * OUT_DIMN + h * HDIM + d] * aedge[h * HDIM + d];
        c_edgeH[h * EDGE_DIMN + k] = s3;  // [h*64+k]
    }
}

// K2: node logits. 16 lanes per row (2 float4 each), DPP reduce, all 4 heads.
__global__ __launch_bounds__(256) void k_node_logits(
    const float* __restrict__ X, const float* __restrict__ cH,
    float* __restrict__ outl, int N) {
    int t = threadIdx.x;
    int row = blockIdx.x * 16 + (t >> 4);
    int q = t & 15;
    if (row >= N) return;
    const float4* X4 = (const float4*)X;
    const float4* C4 = (const float4*)cH;
    float4 xa = X4[(size_t)row * 32 + q];
    float4 xb = X4[(size_t)row * 32 + 16 + q];
    float s0, s1, s2, s3;
    #pragma unroll
    for (int h = 0; h < 4; ++h) {
        float4 ca = C4[h * 32 + q];
        float4 cb = C4[h * 32 + 16 + q];
        float v = xa.x * ca.x + xa.y * ca.y + xa.z * ca.z + xa.w * ca.w
                + xb.x * cb.x + xb.y * cb.y + xb.z * cb.z + xb.w * cb.w;
        v = sum16(v);
        if (h == 0) s0 = v; else if (h == 1) s1 = v;
        else if (h == 2) s2 = v; else s3 = v;
    }
    float v = (q == 0) ? s0 : (q == 1) ? s1 : (q == 2) ? s2 : s3;
    if (q < 4) outl[(size_t)row * 4 + q] = v;
}

// K3a: degree histogram over dst indices.
__global__ __launch_bounds__(256) void k_hist(
    const int* __restrict__ dstI, int* __restrict__ counts) {
    int e = blockIdx.x * 256 + threadIdx.x;
    if (e < NE) atomicAdd(&counts[dstI[e]], 1);
}

// K3b-1: per-block (1024-wide) exclusive scan, block totals to bsum.
__global__ __launch_bounds__(1024) void k_scan_part(
    const int* __restrict__ cnt, int* __restrict__ offs, int* __restrict__ bsum) {
    __shared__ int wsum[16];
    int t = threadIdx.x, b = blockIdx.x;
    int idx = b * 1024 + t;
    int lane = t & 63, w = t >> 6;
    int c = (idx < N_DSTN) ? cnt[idx] : 0;
    int incl = c;
    #pragma unroll
    for (int off = 1; off < 64; off <<= 1) {
        int v = __shfl_up(incl, off, 64);
        if (lane >= off) incl += v;
    }
    if (lane == 63) wsum[w] = incl;
    __syncthreads();
    if (t == 0) {
        int run = 0;
        #pragma unroll
        for (int qq = 0; qq < 16; ++qq) { int v = wsum[qq]; wsum[qq] = run; run += v; }
        bsum[b] = run;
    }
    __syncthreads();
    if (idx < N_DSTN) offs[idx] = wsum[w] + incl - c;
}

// K3b-2: exclusive scan of the 49 block sums; writes grand total to offs[N].
__global__ __launch_bounds__(64) void k_scan_mid(
    int* __restrict__ bsum, int* __restrict__ offs, int nb) {
    int l = threadIdx.x;
    int v = (l < nb) ? bsum[l] : 0;
    int incl = v;
    #pragma unroll
    for (int off = 1; off < 64; off <<= 1) {
        int u = __shfl_up(incl, off, 64);
        if (l >= off) incl += u;
    }
    if (l < nb) bsum[l] = incl - v;
    if (l == 63) offs[N_DSTN] = incl;
}

// K3b-3: add block base, copy to cursor.
__global__ __launch_bounds__(1024) void k_scan_add(
    int* __restrict__ offs, int* __restrict__ cursor, const int* __restrict__ bsum) {
    int idx = blockIdx.x * 1024 + threadIdx.x;
    if (idx < N_DSTN) {
        int v = offs[idx] + bsum[blockIdx.x];
        offs[idx] = v;
        cursor[idx] = v;
    }
}

// K3c: scatter edge ids into dst-sorted order.
__global__ __launch_bounds__(256) void k_scatter(
    const int* __restrict__ dstI, int* __restrict__ cursor,
    int* __restrict__ perm) {
    int e = blockIdx.x * 256 + threadIdx.x;
    if (e < NE) {
        int d = dstI[e];
        int pos = atomicAdd(&cursor[d], 1);
        perm[pos] = e;
    }
}

// K4: hs_half = (h_src @ W_src)[:, c0:c0+64], stored fp16.
__global__ __launch_bounds__(256) void k_gemm_half(
    const float* __restrict__ A, const float* __restrict__ W,
    half_t* __restrict__ C, int M, int c0) {
    __shared__ float As[64][68];
    __shared__ float Ws[64][68];
    int t = threadIdx.x;
    int tx = t & 15, ty = t >> 4;
    int rowbase = blockIdx.x * 64;
    float acc[4][4];
    #pragma unroll
    for (int i = 0; i < 4; ++i)
        #pragma unroll
        for (int j = 0; j < 4; ++j) acc[i][j] = 0.f;

    for (int kc = 0; kc < IN_DIM; kc += 64) {
        #pragma unroll
        for (int p = 0; p < 4; ++p) {          // A tile: 64x64
            int flat = p * 1024 + t * 4;
            int r = flat >> 6, ck = flat & 63;
            float4 v = make_float4(0.f, 0.f, 0.f, 0.f);
            if (rowbase + r < M)
                v = *(const float4*)(A + (size_t)(rowbase + r) * IN_DIM + kc + ck);
            *(float4*)(&As[r][ck]) = v;
        }
        #pragma unroll
        for (int p = 0; p < 4; ++p) {          // W tile: 64x64 (cols c0..c0+63)
            int flat = p * 1024 + t * 4;
            int kk = flat >> 6, col = flat & 63;
            *(float4*)(&Ws[kk][col]) =
                *(const float4*)(W + (size_t)(kc + kk) * OUT_DIMN + c0 + col);
        }
        __syncthreads();
        #pragma unroll
        for (int k = 0; k < 64; ++k) {
            float a[4], b[4];
            #pragma unroll
            for (int i = 0; i < 4; ++i) a[i] = As[ty * 4 + i][k];
            #pragma unroll
            for (int j = 0; j < 4; ++j) b[j] = Ws[k][tx + j * 16];
            #pragma unroll
            for (int i = 0; i < 4; ++i)
                #pragma unroll
                for (int j = 0; j < 4; ++j) acc[i][j] += a[i] * b[j];
        }
        __syncthreads();
    }
    #pragma unroll
    for (int i = 0; i < 4; ++i) {
        int row = rowbase + ty * 4 + i;
        if (row < M) {
            #pragma unroll
            for (int j = 0; j < 4; ++j)
                C[(size_t)row * 64 + tx + j * 16] = (half_t)acc[i][j];
        }
    }
}

// K5: gather-aggregate, depth-3 software pipeline + DPP-reduced dot.
// One wave per dst. Lane l: q=l&15 reads float4 of EF row (4 groups share the
// 256B line via L1); head h = pass*2 + (l>>5); 16-lane DPP rotate-add gives
// every lane its head's full 64-dot. Lane owns out col pass*64+l. No DS ops.
// Pipeline: perm issued 5 ahead, srcI 4 ahead, EF/esrc/hsH 3 ahead.
__global__ __launch_bounds__(256) void k_gather(
    const int* __restrict__ offs, const int* __restrict__ perm,
    const int* __restrict__ srcI,
    const float* __restrict__ EF, const float* __restrict__ ceH,
    const float* __restrict__ esrc, const float* __restrict__ edstl,
    const half_t* __restrict__ hsH, float* __restrict__ out, int pass) {
    int d = blockIdx.x * 4 + (threadIdx.x >> 6);
    if (d >= N_DSTN) return;
    int l = threadIdx.x & 63;
    int q = l & 15;
    int h = pass * 2 + (l >> 5);
    int start = offs[d], end = offs[d + 1];
    int n = end - start;
    if (n <= 0) { out[(size_t)d * OUT_DIMN + pass * 64 + l] = 0.f; return; }

    const float4* EF4 = (const float4*)EF;
    float4 c4 = ((const float4*)ceH)[h * 16 + q];
    float ed = edstl[(size_t)d * 4 + h];
    int end1 = end - 1;
    #define PCLAMP(i) perm[(start + (i) < end) ? (start + (i)) : end1]

    // prologue: stages hold edges 0,1,2; eid for 3,4; si for 3.
    int a0 = PCLAMP(0), a1 = PCLAMP(1), a2 = PCLAMP(2);
    int e3 = PCLAMP(3), e4 = PCLAMP(4);
    int b0 = srcI[a0], b1 = srcI[a1], b2 = srcI[a2];
    int s3 = srcI[e3];
    float4 v0 = EF4[(size_t)a0 * 16 + q];
    float4 v1 = EF4[(size_t)a1 * 16 + q];
    float4 v2 = EF4[(size_t)a2 * 16 + q];
    float f0 = esrc[(size_t)b0 * 4 + h];
    float f1 = esrc[(size_t)b1 * 4 + h];
    float f2 = esrc[(size_t)b2 * 4 + h];
    half_t g0 = hsH[(size_t)b0 * 64 + l];
    half_t g1 = hsH[(size_t)b1 * 64 + l];
    half_t g2 = hsH[(size_t)b2 * 64 + l];

    float acc = 0.f, den = 0.f;
    for (int i = 0; i < n; ++i) {
        int e5 = PCLAMP(i + 5);                    // no deps
        int s4 = srcI[e4];                         // e4 arrived (issued i-1)
        float4 vN = EF4[(size_t)e3 * 16 + q];      // e3 arrived (issued i-2)
        float  fN = esrc[(size_t)s3 * 4 + h];      // s3 arrived (issued i-1)
        half_t gN = hsH[(size_t)s3 * 64 + l];

        float s = v0.x * c4.x + v0.y * c4.y + v0.z * c4.z + v0.w * c4.w;
        s = sum16(s);                              // 4 DPP adds, no LDS
        float z = f0 + ed + s;
        z = z > 0.f ? z : 0.2f * z;
        float ez = __expf(z);
        den += ez;
        acc += ez * (float)g0;

        v0 = v1; v1 = v2; v2 = vN;
        f0 = f1; f1 = f2; f2 = fN;
        g0 = g1; g1 = g2; g2 = gN;
        e3 = e4; e4 = e5; s3 = s4;
    }
    #undef PCLAMP
    out[(size_t)d * OUT_DIMN + pass * 64 + l] = acc / (den + 1e-8f);
}

extern "C" void kernel_launch(void* const* d_in, const int* in_sizes, int n_in,
                              void* d_out, int out_size, void* d_ws, size_t ws_size,
                              hipStream_t stream) {
    const float* h_src     = (const float*)d_in[0];
    const float* h_dst     = (const float*)d_in[1];
    const float* edge_feat = (const float*)d_in[2];
    const int*   eidx      = (const int*)d_in[3];   // [2, E] int32
    const float* Wsrc      = (const float*)d_in[4];
    const float* Wdst      = (const float*)d_in[5];
    const float* Wedge     = (const float*)d_in[6];
    const float* asrc      = (const float*)d_in[7];
    const float* adst      = (const float*)d_in[8];
    const float* aedge     = (const float*)d_in[9];
    float* out = (float*)d_out;

    char* W = (char*)d_ws;
    half_t* hsH    = (half_t*)(W + 0);
    int*   perm    = (int*)(W + 6400000);
    float* esrc    = (float*)(W + 12800000);
    float* edstl   = (float*)(W + 13600000);
    int*   offs    = (int*)(W + 14400000);
    int*   cursor  = (int*)(W + 14600016);
    int*   counts  = (int*)(W + 14800016);
    float* c_srcH  = (float*)(W + 15000016);
    float* c_dstH  = (float*)(W + 15002064);
    float* c_edgeH = (float*)(W + 15004112);
    int*   bsum    = (int*)(W + 15005136);

    const int* srcI = eidx;
    const int* dstI = eidx + NE;

    const int NB_SCAN = (N_DSTN + 1023) / 1024;   // 49

    hipMemsetAsync(counts, 0, N_DSTN * sizeof(int), stream);

    k_combine<<<1, 512, 0, stream>>>(Wsrc, Wdst, Wedge, asrc, adst, aedge,
                                     c_srcH, c_dstH, c_edgeH);
    k_node_logits<<<(N_SRCN + 15) / 16, 256, 0, stream>>>(h_src, c_srcH, esrc, N_SRCN);
    k_node_logits<<<(N_DSTN + 15) / 16, 256, 0, stream>>>(h_dst, c_dstH, edstl, N_DSTN);

    k_hist<<<(NE + 255) / 256, 256, 0, stream>>>(dstI, counts);
    k_scan_part<<<NB_SCAN, 1024, 0, stream>>>(counts, offs, bsum);
    k_scan_mid<<<1, 64, 0, stream>>>(bsum, offs, NB_SCAN);
    k_scan_add<<<NB_SCAN, 1024, 0, stream>>>(offs, cursor, bsum);
    k_scatter<<<(NE + 255) / 256, 256, 0, stream>>>(dstI, cursor, perm);

    k_gemm_half<<<(N_SRCN + 63) / 64, 256, 0, stream>>>(h_src, Wsrc, hsH, N_SRCN, 0);
    k_gather<<<(N_DSTN + 3) / 4, 256, 0, stream>>>(offs, perm, srcI, edge_feat,
                                                   c_edgeH, esrc, edstl, hsH, out, 0);
    k_gemm_half<<<(N_SRCN + 63) / 64, 256, 0, stream>>>(h_src, Wsrc, hsH, N_SRCN, 64);
    k_gather<<<(N_DSTN + 3) / 4, 256, 0, stream>>>(offs, perm, srcI, edge_feat,
                                                   c_edgeH, esrc, edstl, hsH, out, 1);
}

// Round 3
// 1215.889 us; speedup vs baseline: 1.6421x; 1.1553x over previous
//
#include <hip/hip_runtime.h>

typedef _Float16 half_t;

#define N_SRCN 50000
#define N_DSTN 50000
#define NE     1600000
#define IN_DIM 128
#define OUT_DIMN 128
#define EDGE_DIMN 64
#define NHEAD  4
#define HDIM   32

// 16-lane (DPP row) rotate-add full reduction: after 4 steps every lane in each
// 16-lane row holds the row's sum. Pure VALU — no LDS/DS ops.
#define ROR_ADD(x, CTRL) ((x) + __int_as_float(__builtin_amdgcn_update_dpp( \
    0, __float_as_int(x), (CTRL), 0xF, 0xF, false)))
__device__ __forceinline__ float sum16(float s) {
    s = ROR_ADD(s, 0x121);  // row_ror:1
    s = ROR_ADD(s, 0x122);  // row_ror:2
    s = ROR_ADD(s, 0x124);  // row_ror:4
    s = ROR_ADD(s, 0x128);  // row_ror:8
    return s;
}

// ---------------------------------------------------------------------------
// Workspace layout — 15,205,392 bytes total (< 15,206,144 proven safe).
// EF work moved to a streaming scatter pass; gather loop only touches
// sequential (ssrc,w) streams + L2-resident 3.2MB hs quarter.
//   ssrc   u16[1.6M]      @ 0           (3,200,000)  src ids, dst-sorted (u16: N_SRC<65536)
//   wA     f16[1.6M]      @ 3,200,000   (3,200,000)  exp-weights head A, dst-sorted
//   wB     f16[1.6M]      @ 6,400,000   (3,200,000)  exp-weights head B, dst-sorted
//   hs_q   f16[50000*32]  @ 9,600,000   (3,200,000)  quarter of h_src @ W_src
//   esrc   f32[200,000]   @ 12,800,000  (  800,000)  per-src logits [N,4]
//   edstl  f32[200,000]   @ 13,600,000  (  800,000)  per-dst logits [N,4]
//   offs   i32[50001]     @ 14,400,000  (  200,016)  CSR row offsets
//   curA   i32[50000]     @ 14,600,016  (  200,000)  cursor for stream pass A
//   curB   i32[50000]     @ 14,800,016  (  200,000)  cursor for stream pass B
//   counts i32[50000]     @ 15,000,016  (  200,000)  degree histogram
//   c_srcH f32[512]       @ 15,200,016  (    2,048)  head-major [h*128+k]
//   c_dstH f32[512]       @ 15,202,064  (    2,048)
//   c_edgeH f32[256]      @ 15,204,112  (    1,024)  head-major [h*64+k]
//   bsum   i32[64]        @ 15,205,136  (      256)  scan block sums
// ---------------------------------------------------------------------------

// K1: fold attention vectors through weights (head-major outputs).
__global__ __launch_bounds__(512) void k_combine(
    const float* __restrict__ Wsrc, const float* __restrict__ Wdst,
    const float* __restrict__ Wedge,
    const float* __restrict__ asrc, const float* __restrict__ adst,
    const float* __restrict__ aedge,
    float* __restrict__ c_srcH, float* __restrict__ c_dstH,
    float* __restrict__ c_edgeH) {
    int t = threadIdx.x;           // k = t>>2 (0..127), h = t&3
    int k = t >> 2, h = t & 3;
    float s1 = 0.f, s2 = 0.f;
    #pragma unroll
    for (int d = 0; d < HDIM; ++d) {
        s1 += Wsrc[k * OUT_DIMN + h * HDIM + d] * asrc[h * HDIM + d];
        s2 += Wdst[k * OUT_DIMN + h * HDIM + d] * adst[h * HDIM + d];
    }
    c_srcH[h * IN_DIM + k] = s1;
    c_dstH[h * IN_DIM + k] = s2;
    if (t < EDGE_DIMN * NHEAD) {   // k = 0..63
        float s3 = 0.f;
        #pragma unroll
        for (int d = 0; d < HDIM; ++d)
            s3 += Wedge[k * OUT_DIMN + h * HDIM + d] * aedge[h * HDIM + d];
        c_edgeH[h * EDGE_DIMN + k] = s3;  // [h*64+k]
    }
}

// K2: node logits. 16 lanes per row (2 float4 each), DPP reduce, all 4 heads.
__global__ __launch_bounds__(256) void k_node_logits(
    const float* __restrict__ X, const float* __restrict__ cH,
    float* __restrict__ outl, int N) {
    int t = threadIdx.x;
    int row = blockIdx.x * 16 + (t >> 4);
    int q = t & 15;
    if (row >= N) return;
    const float4* X4 = (const float4*)X;
    const float4* C4 = (const float4*)cH;
    float4 xa = X4[(size_t)row * 32 + q];
    float4 xb = X4[(size_t)row * 32 + 16 + q];
    float s0, s1, s2, s3;
    #pragma unroll
    for (int h = 0; h < 4; ++h) {
        float4 ca = C4[h * 32 + q];
        float4 cb = C4[h * 32 + 16 + q];
        float v = xa.x * ca.x + xa.y * ca.y + xa.z * ca.z + xa.w * ca.w
                + xb.x * cb.x + xb.y * cb.y + xb.z * cb.z + xb.w * cb.w;
        v = sum16(v);
        if (h == 0) s0 = v; else if (h == 1) s1 = v;
        else if (h == 2) s2 = v; else s3 = v;
    }
    float v = (q == 0) ? s0 : (q == 1) ? s1 : (q == 2) ? s2 : s3;
    if (q < 4) outl[(size_t)row * 4 + q] = v;
}

// K3a: degree histogram over dst indices.
__global__ __launch_bounds__(256) void k_hist(
    const int* __restrict__ dstI, int* __restrict__ counts) {
    int e = blockIdx.x * 256 + threadIdx.x;
    if (e < NE) atomicAdd(&counts[dstI[e]], 1);
}

// K3b-1: per-block (1024-wide) exclusive scan, block totals to bsum.
__global__ __launch_bounds__(1024) void k_scan_part(
    const int* __restrict__ cnt, int* __restrict__ offs, int* __restrict__ bsum) {
    __shared__ int wsum[16];
    int t = threadIdx.x, b = blockIdx.x;
    int idx = b * 1024 + t;
    int lane = t & 63, w = t >> 6;
    int c = (idx < N_DSTN) ? cnt[idx] : 0;
    int incl = c;
    #pragma unroll
    for (int off = 1; off < 64; off <<= 1) {
        int v = __shfl_up(incl, off, 64);
        if (lane >= off) incl += v;
    }
    if (lane == 63) wsum[w] = incl;
    __syncthreads();
    if (t == 0) {
        int run = 0;
        #pragma unroll
        for (int qq = 0; qq < 16; ++qq) { int v = wsum[qq]; wsum[qq] = run; run += v; }
        bsum[b] = run;
    }
    __syncthreads();
    if (idx < N_DSTN) offs[idx] = wsum[w] + incl - c;
}

// K3b-2: exclusive scan of the 49 block sums; writes grand total to offs[N].
__global__ __launch_bounds__(64) void k_scan_mid(
    int* __restrict__ bsum, int* __restrict__ offs, int nb) {
    int l = threadIdx.x;
    int v = (l < nb) ? bsum[l] : 0;
    int incl = v;
    #pragma unroll
    for (int off = 1; off < 64; off <<= 1) {
        int u = __shfl_up(incl, off, 64);
        if (l >= off) incl += u;
    }
    if (l < nb) bsum[l] = incl - v;
    if (l == 63) offs[N_DSTN] = incl;
}

// K3b-3: add block base, copy to both cursors.
__global__ __launch_bounds__(1024) void k_scan_add(
    int* __restrict__ offs, int* __restrict__ curA, int* __restrict__ curB,
    const int* __restrict__ bsum) {
    int idx = blockIdx.x * 1024 + threadIdx.x;
    if (idx < N_DSTN) {
        int v = offs[idx] + bsum[blockIdx.x];
        offs[idx] = v;
        curA[idx] = v;
        curB[idx] = v;
    }
}

// K4: streaming edge pass for heads (ha, hb). 16 lanes per edge, coalesced EF
// read (1KB per wave), DPP dot for both heads, exp, then scatter
// (u16 src, fp16 wA, fp16 wB) to the dst-sorted slot via atomic cursor.
// Replaces the old perm-scatter AND removes EF from the gather loop.
__global__ __launch_bounds__(256) void k_edge_stream(
    const float* __restrict__ EF,
    const int* __restrict__ srcI, const int* __restrict__ dstI,
    const float* __restrict__ esrc, const float* __restrict__ edstl,
    const float* __restrict__ ceH, int* __restrict__ cursor,
    unsigned short* __restrict__ ssrc,
    half_t* __restrict__ wAo, half_t* __restrict__ wBo,
    int ha, int hb) {
    int t = threadIdx.x;
    int e = blockIdx.x * 16 + (t >> 4);
    if (e >= NE) return;
    int q = t & 15;
    const float4* EF4 = (const float4*)EF;
    const float4* CE4 = (const float4*)ceH;
    float4 v  = EF4[(size_t)e * 16 + q];
    float4 cA = CE4[ha * 16 + q];
    float4 cB = CE4[hb * 16 + q];
    float sA = v.x * cA.x + v.y * cA.y + v.z * cA.z + v.w * cA.w;
    float sB = v.x * cB.x + v.y * cB.y + v.z * cB.z + v.w * cB.w;
    sA = sum16(sA);
    sB = sum16(sB);   // all 16 lanes hold both head dots
    int pos = 0;
    if (q < 2) {
        int si = srcI[e], di = dstI[e];
        int h = q ? hb : ha;
        float s = q ? sB : sA;
        float z = esrc[(size_t)si * 4 + h] + edstl[(size_t)di * 4 + h] + s;
        z = z > 0.f ? z : 0.2f * z;
        float ez = __expf(z);
        if (q == 0) pos = atomicAdd(&cursor[di], 1);
        pos = __shfl(pos, (t & 63) & ~15, 64);   // broadcast from group lane 0
        if (q == 0) {
            ssrc[pos] = (unsigned short)si;
            wAo[pos] = (half_t)ez;
        } else {
            wBo[pos] = (half_t)ez;
        }
    }
}

// K5: hs_q = (h_src @ W_src)[:, c0:c0+32], stored fp16. M=64/block, N=32.
__global__ __launch_bounds__(256) void k_gemm_q(
    const float* __restrict__ A, const float* __restrict__ W,
    half_t* __restrict__ C, int M, int c0) {
    __shared__ float As[64][68];
    __shared__ float Ws[64][36];
    int t = threadIdx.x;
    int tx = t & 7, ty = t >> 3;   // tx: 8 col slots, ty: 32 row slots
    int rowbase = blockIdx.x * 64;
    float acc[2][4];
    #pragma unroll
    for (int i = 0; i < 2; ++i)
        #pragma unroll
        for (int j = 0; j < 4; ++j) acc[i][j] = 0.f;

    for (int kc = 0; kc < IN_DIM; kc += 64) {
        #pragma unroll
        for (int p = 0; p < 4; ++p) {          // A tile: 64x64
            int flat = p * 1024 + t * 4;
            int r = flat >> 6, ck = flat & 63;
            float4 v = make_float4(0.f, 0.f, 0.f, 0.f);
            if (rowbase + r < M)
                v = *(const float4*)(A + (size_t)(rowbase + r) * IN_DIM + kc + ck);
            *(float4*)(&As[r][ck]) = v;
        }
        #pragma unroll
        for (int p = 0; p < 2; ++p) {          // W tile: 64x32 (cols c0..c0+31)
            int flat = p * 1024 + t * 4;
            int kk = flat >> 5, col = flat & 31;
            *(float4*)(&Ws[kk][col]) =
                *(const float4*)(W + (size_t)(kc + kk) * OUT_DIMN + c0 + col);
        }
        __syncthreads();
        #pragma unroll
        for (int k = 0; k < 64; ++k) {
            float a[2], b[4];
            #pragma unroll
            for (int i = 0; i < 2; ++i) a[i] = As[ty * 2 + i][k];
            #pragma unroll
            for (int j = 0; j < 4; ++j) b[j] = Ws[k][tx + j * 8];
            #pragma unroll
            for (int i = 0; i < 2; ++i)
                #pragma unroll
                for (int j = 0; j < 4; ++j) acc[i][j] += a[i] * b[j];
        }
        __syncthreads();
    }
    #pragma unroll
    for (int i = 0; i < 2; ++i) {
        int row = rowbase + ty * 2 + i;
        if (row < M) {
            #pragma unroll
            for (int j = 0; j < 4; ++j)
                C[(size_t)row * 32 + tx + j * 8] = (half_t)acc[i][j];
        }
    }
}

// K6: gather for one head. One wave per dst; half-waves split the edge list
// (halving serial depth); lane owns col hcol + (l&31). All loop loads are
// sequential streams (ssrc, w) or 64B gathers into the L2-resident 3.2MB hs_q.
// Depth-2 pipeline; per-edge body is 1 cvt + 2 FMA.
__global__ __launch_bounds__(256) void k_gather(
    const int* __restrict__ offs, const unsigned short* __restrict__ ssrc,
    const half_t* __restrict__ wH, const half_t* __restrict__ hs_q,
    float* __restrict__ out, int hcol) {
    int d = blockIdx.x * 4 + (threadIdx.x >> 6);
    if (d >= N_DSTN) return;
    int l = threadIdx.x & 63;
    int half = l >> 5, c = l & 31;
    int start = offs[d], end = offs[d + 1];
    int n = end - start;
    if (n <= 0) {
        if (half == 0) out[(size_t)d * OUT_DIMN + hcol + c] = 0.f;
        return;
    }
    int cntA = (n + 1) >> 1;
    int myStart = start + (half ? cntA : 0);
    int myN = half ? (n - cntA) : cntA;
    int lim = (myN > 0) ? (myN - 1) : 0;
    #define RIDX(j) (myStart + (((j) < lim) ? (j) : lim))

    unsigned short s0 = ssrc[RIDX(0)], s1 = ssrc[RIDX(1)];
    half_t w0 = wH[RIDX(0)], w1 = wH[RIDX(1)];
    half_t h0 = hs_q[(size_t)s0 * 32 + c];
    float acc = 0.f, den = 0.f;
    for (int j = 0; j < cntA; ++j) {
        unsigned short s2 = ssrc[RIDX(j + 2)];
        half_t w2 = wH[RIDX(j + 2)];
        half_t h1 = hs_q[(size_t)s1 * 32 + c];
        float wf = (j < myN) ? (float)w0 : 0.f;
        den += wf;
        acc = fmaf(wf, (float)h0, acc);
        s0 = s1; s1 = s2; w0 = w1; w1 = w2; h0 = h1;
    }
    #undef RIDX
    acc += __shfl_xor(acc, 32, 64);
    den += __shfl_xor(den, 32, 64);
    if (half == 0) out[(size_t)d * OUT_DIMN + hcol + c] = acc / (den + 1e-8f);
}

extern "C" void kernel_launch(void* const* d_in, const int* in_sizes, int n_in,
                              void* d_out, int out_size, void* d_ws, size_t ws_size,
                              hipStream_t stream) {
    const float* h_src     = (const float*)d_in[0];
    const float* h_dst     = (const float*)d_in[1];
    const float* edge_feat = (const float*)d_in[2];
    const int*   eidx      = (const int*)d_in[3];   // [2, E] int32
    const float* Wsrc      = (const float*)d_in[4];
    const float* Wdst      = (const float*)d_in[5];
    const float* Wedge     = (const float*)d_in[6];
    const float* asrc      = (const float*)d_in[7];
    const float* adst      = (const float*)d_in[8];
    const float* aedge     = (const float*)d_in[9];
    float* out = (float*)d_out;

    char* W = (char*)d_ws;
    unsigned short* ssrc = (unsigned short*)(W + 0);
    half_t* wA     = (half_t*)(W + 3200000);
    half_t* wB     = (half_t*)(W + 6400000);
    half_t* hs_q   = (half_t*)(W + 9600000);
    float* esrc    = (float*)(W + 12800000);
    float* edstl   = (float*)(W + 13600000);
    int*   offs    = (int*)(W + 14400000);
    int*   curA    = (int*)(W + 14600016);
    int*   curB    = (int*)(W + 14800016);
    int*   counts  = (int*)(W + 15000016);
    float* c_srcH  = (float*)(W + 15200016);
    float* c_dstH  = (float*)(W + 15202064);
    float* c_edgeH = (float*)(W + 15204112);
    int*   bsum    = (int*)(W + 15205136);

    const int* srcI = eidx;
    const int* dstI = eidx + NE;

    const int NB_SCAN = (N_DSTN + 1023) / 1024;   // 49

    hipMemsetAsync(counts, 0, N_DSTN * sizeof(int), stream);

    k_combine<<<1, 512, 0, stream>>>(Wsrc, Wdst, Wedge, asrc, adst, aedge,
                                     c_srcH, c_dstH, c_edgeH);
    k_node_logits<<<(N_SRCN + 15) / 16, 256, 0, stream>>>(h_src, c_srcH, esrc, N_SRCN);
    k_node_logits<<<(N_DSTN + 15) / 16, 256, 0, stream>>>(h_dst, c_dstH, edstl, N_DSTN);

    k_hist<<<(NE + 255) / 256, 256, 0, stream>>>(dstI, counts);
    k_scan_part<<<NB_SCAN, 1024, 0, stream>>>(counts, offs, bsum);
    k_scan_mid<<<1, 64, 0, stream>>>(bsum, offs, NB_SCAN);
    k_scan_add<<<NB_SCAN, 1024, 0, stream>>>(offs, curA, curB, bsum);

    // heads 0,1
    k_edge_stream<<<(NE + 15) / 16, 256, 0, stream>>>(
        edge_feat, srcI, dstI, esrc, edstl, c_edgeH, curA, ssrc, wA, wB, 0, 1);
    k_gemm_q<<<(N_SRCN + 63) / 64, 256, 0, stream>>>(h_src, Wsrc, hs_q, N_SRCN, 0);
    k_gather<<<(N_DSTN + 3) / 4, 256, 0, stream>>>(offs, ssrc, wA, hs_q, out, 0);
    k_gemm_q<<<(N_SRCN + 63) / 64, 256, 0, stream>>>(h_src, Wsrc, hs_q, N_SRCN, 32);
    k_gather<<<(N_DSTN + 3) / 4, 256, 0, stream>>>(offs, ssrc, wB, hs_q, out, 32);

    // heads 2,3 (rewrites ssrc/wA/wB with pass-B ordering — consistent within pass)
    k_edge_stream<<<(NE + 15) / 16, 256, 0, stream>>>(
        edge_feat, srcI, dstI, esrc, edstl, c_edgeH, curB, ssrc, wA, wB, 2, 3);
    k_gemm_q<<<(N_SRCN + 63) / 64, 256, 0, stream>>>(h_src, Wsrc, hs_q, N_SRCN, 64);
    k_gather<<<(N_DSTN + 3) / 4, 256, 0, stream>>>(offs, ssrc, wA, hs_q, out, 64);
    k_gemm_q<<<(N_SRCN + 63) / 64, 256, 0, stream>>>(h_src, Wsrc, hs_q, N_SRCN, 96);
    k_gather<<<(N_DSTN + 3) / 4, 256, 0, stream>>>(offs, ssrc, wB, hs_q, out, 96);
}